// Round 4
// baseline (441.961 us; speedup 1.0000x reference)
//
#include <hip/hip_runtime.h>
#include <hip/hip_bf16.h>
#include <stdint.h>

#define N_TOKENS 8192
#define IN_F 4096
#define OUT_F 4096

#define BM 256
#define BN 256
#define BKB 64              // K-bytes (i8 elems) per K-tile
#define NKT (IN_F / BKB)    // 64 K-tiles

typedef int int32x4 __attribute__((ext_vector_type(4)));

__device__ __forceinline__ void gload_lds16(const signed char* g, signed char* lds) {
  __builtin_amdgcn_global_load_lds(
      (const __attribute__((address_space(1))) void*)g,
      (__attribute__((address_space(3))) void*)lds, 16, 0, 0);
}

// ---- pack: int32 -> int8, grid-stride; 16B coalesced reads, 4B writes ----
__global__ void pack_kernel(const int4* __restrict__ xs, const int4* __restrict__ ws,
                            uchar4* __restrict__ xd, uchar4* __restrict__ wd,
                            int n4x, int n4tot) {
  const int stride = gridDim.x * blockDim.x;
  for (int i = blockIdx.x * blockDim.x + threadIdx.x; i < n4tot; i += stride) {
    int4 v;
    if (i < n4x) v = xs[i];
    else v = ws[i - n4x];
    uchar4 p;
    p.x = (unsigned char)(v.x & 255);
    p.y = (unsigned char)(v.y & 255);
    p.z = (unsigned char)(v.z & 255);
    p.w = (unsigned char)(v.w & 255);
    if (i < n4x) xd[i] = p;
    else wd[i - n4x] = p;
  }
}

// ---- int8 MFMA GEMM, 256x256 tile, 8 waves, 3-buffer counted-vmcnt pipeline ----
// A: [N_TOKENS][IN_F] i8, B: [OUT_F][IN_F] i8; C = A @ B^T, requant epilogue.
__global__ __launch_bounds__(512, 2) void gemm_i8(
    const signed char* __restrict__ A, const signed char* __restrict__ B,
    const int* __restrict__ bias, const float* __restrict__ wscale,
    int* __restrict__ out) {
  // 3 rotating buffers: tile t reads buf t%3, tile t+2 stages into (t+2)%3.
  // The overwritten buf ((t-1)%3) had its reads drained by lgkmcnt(0) at the
  // previous boundary barrier -> no WAR race.
  __shared__ __align__(16) signed char sA[3][BM * BKB];  // 3 x 16 KB
  __shared__ __align__(16) signed char sB[3][BN * BKB];  // 3 x 16 KB

  const int tid = threadIdx.x;
  const int lane = tid & 63;
  const int w = tid >> 6;  // wave 0..7
  const int wr = w >> 2;   // 0..1 : M-panel (128 rows)
  const int wc = w & 3;    // 0..3 : N-panel (64 cols)

  const int brow = blockIdx.y * BM;
  const int bcol = blockIdx.x * BN;

  // staging: wave w covers rows [w*16, w*16+16) and +128, 4 chunks/row.
  // LDS dest is linear lane*16 (gload_lds requirement); bank-swizzle done by
  // pre-swizzling the GLOBAL chunk: c_src = c ^ ((row>>1)&3)  (involution).
  const int csrc = (((lane & 3) ^ ((lane >> 3) & 3)) << 4);
  const int r0 = w * 16 + (lane >> 2);
  const signed char* gA0 = A + (size_t)(brow + r0) * IN_F + csrc;
  const signed char* gB0 = B + (size_t)(bcol + r0) * IN_F + csrc;
  const int ldst = w * 1024 + lane * 16;

#define STAGE(tt, bf)                                                  \
  do {                                                                 \
    const size_t ko = (size_t)(tt)*BKB;                                \
    gload_lds16(gA0 + ko, &sA[bf][ldst]);                              \
    gload_lds16(gA0 + ko + (size_t)128 * IN_F, &sA[bf][ldst + 8192]);  \
    gload_lds16(gB0 + ko, &sB[bf][ldst]);                              \
    gload_lds16(gB0 + ko + (size_t)128 * IN_F, &sB[bf][ldst + 8192]);  \
  } while (0)

  // fragment reads: row = panel + frag*16 + (lane&15); since panel/frag are
  // multiples of 16, (row>>1)&3 == (lane>>1)&3 -> lane-only chunk swizzle.
  const int cfrag = (((lane >> 4) ^ ((lane >> 1) & 3)) << 4);
  const int aoff = (wr * 128 + (lane & 15)) * BKB + cfrag;  // + m*1024
  const int boff = (wc * 64 + (lane & 15)) * BKB + cfrag;   // + n*1024

  int32x4 acc[8][4];
#pragma unroll
  for (int m = 0; m < 8; ++m)
#pragma unroll
    for (int n = 0; n < 4; ++n) acc[m][n] = (int32x4){0, 0, 0, 0};

  // prologue: fill buffers 0 and 1, publish tile 0 (vmcnt(4): t1's 4 in flight)
  STAGE(0, 0);
  STAGE(1, 1);
  asm volatile("s_waitcnt vmcnt(4)" ::: "memory");
  __builtin_amdgcn_s_barrier();

  int bufR = 0, bufS = 2;
  for (int t = 0; t < NKT; ++t) {
    if (t < NKT - 2) STAGE(t + 2, bufS);

    int32x4 a[8], b[4];
    // ---- phase A: C-half m=0..3 ----
#pragma unroll
    for (int n = 0; n < 4; ++n) b[n] = *(const int32x4*)&sB[bufR][boff + n * 1024];
#pragma unroll
    for (int m = 0; m < 4; ++m) a[m] = *(const int32x4*)&sA[bufR][aoff + m * 1024];
    __builtin_amdgcn_s_setprio(1);
#pragma unroll
    for (int m = 0; m < 4; ++m)
#pragma unroll
      for (int n = 0; n < 4; ++n)
        acc[m][n] = __builtin_amdgcn_mfma_i32_16x16x64_i8(a[m], b[n], acc[m][n], 0, 0, 0);
    __builtin_amdgcn_s_setprio(0);
    __builtin_amdgcn_s_barrier();  // mid-tile lockstep
    // ---- phase B: C-half m=4..7 ----
#pragma unroll
    for (int m = 4; m < 8; ++m) a[m] = *(const int32x4*)&sA[bufR][aoff + m * 1024];
    __builtin_amdgcn_s_setprio(1);
#pragma unroll
    for (int m = 4; m < 8; ++m)
#pragma unroll
      for (int n = 0; n < 4; ++n)
        acc[m][n] = __builtin_amdgcn_mfma_i32_16x16x64_i8(a[m], b[n], acc[m][n], 0, 0, 0);
    __builtin_amdgcn_s_setprio(0);

    // boundary: drain my ds_reads (lgkm), publish tile t+1 (counted vmcnt:
    // t+2's 4 loads stay in flight -- never drain vmcnt to 0 mid-loop).
    if (t < NKT - 2) {
      asm volatile("s_waitcnt vmcnt(4) lgkmcnt(0)" ::: "memory");
      __builtin_amdgcn_s_barrier();
    } else if (t == NKT - 2) {
      asm volatile("s_waitcnt vmcnt(0) lgkmcnt(0)" ::: "memory");
      __builtin_amdgcn_s_barrier();
    }
    bufR = (bufR == 2) ? 0 : bufR + 1;
    bufS = (bufS == 2) ? 0 : bufS + 1;
  }
#undef STAGE

  // epilogue: C/D layout col=lane&15, row=(lane>>4)*4+reg. OUTPUT IS INT32.
  const int colb = bcol + wc * 64 + (lane & 15);
  const int rowb = brow + wr * 128 + ((lane >> 4) << 2);
#pragma unroll
  for (int n = 0; n < 4; ++n) {
    const int col = colb + n * 16;
    const float s = 0.02f * wscale[col] / 0.05f;
    const int bz = bias[col];
#pragma unroll
    for (int m = 0; m < 8; ++m) {
      const int row0 = rowb + m * 16;
#pragma unroll
      for (int r = 0; r < 4; ++r) {
        float f = (float)(acc[m][n][r] + bz) * s;
        f = rintf(f);                        // round-half-even == jnp.round
        f = fminf(127.f, fmaxf(-128.f, f));  // clip
        out[(size_t)(row0 + r) * OUT_F + col] = (int)f;
      }
    }
  }
}

extern "C" void kernel_launch(void* const* d_in, const int* in_sizes, int n_in,
                              void* d_out, int out_size, void* d_ws, size_t ws_size,
                              hipStream_t stream) {
  const int* x = (const int*)d_in[0];        // [8192,4096] values in [-128,127]
  const int* w = (const int*)d_in[1];        // [4096,4096]
  const int* bias = (const int*)d_in[2];     // [4096]
  const float* wsc = (const float*)d_in[3];  // [4096]
  int* out = (int*)d_out;

  signed char* xp = (signed char*)d_ws;            // 32 MB
  signed char* wp = xp + (size_t)N_TOKENS * IN_F;  // 16 MB

  const int n4x = N_TOKENS * IN_F / 4;
  const int n4w = OUT_F * IN_F / 4;
  const int n4tot = n4x + n4w;

  pack_kernel<<<2048, 256, 0, stream>>>((const int4*)x, (const int4*)w,
                                        (uchar4*)xp, (uchar4*)wp, n4x, n4tot);

  dim3 grid(OUT_F / BN, N_TOKENS / BM);  // (16, 32) = 512 blocks
  gemm_i8<<<grid, dim3(512), 0, stream>>>(xp, wp, bias, wsc, out);
}

// Round 7
// 409.323 us; speedup vs baseline: 1.0797x; 1.0797x over previous
//
#include <hip/hip_runtime.h>
#include <hip/hip_bf16.h>
#include <stdint.h>

#define N_TOKENS 8192
#define IN_F 4096
#define OUT_F 4096

#define BM 256
#define BN 256
#define BKB 128            // K-bytes (i8 elems) per K-tile (2 MFMA k-slices)
#define NKT (IN_F / BKB)   // 32 K-tiles

typedef int int32x4 __attribute__((ext_vector_type(4)));

__device__ __forceinline__ void gload_lds16(const signed char* g, signed char* lds) {
  __builtin_amdgcn_global_load_lds(
      (const __attribute__((address_space(1))) void*)g,
      (__attribute__((address_space(3))) void*)lds, 16, 0, 0);
}

// ---- pack: int32 -> int8, grid-stride; 16B coalesced reads, 4B writes ----
__global__ void pack_kernel(const int4* __restrict__ xs, const int4* __restrict__ ws,
                            uchar4* __restrict__ xd, uchar4* __restrict__ wd,
                            int n4x, int n4tot) {
  const int stride = gridDim.x * blockDim.x;
  for (int i = blockIdx.x * blockDim.x + threadIdx.x; i < n4tot; i += stride) {
    int4 v;
    if (i < n4x) v = xs[i];
    else v = ws[i - n4x];
    uchar4 p;
    p.x = (unsigned char)(v.x & 255);
    p.y = (unsigned char)(v.y & 255);
    p.z = (unsigned char)(v.z & 255);
    p.w = (unsigned char)(v.w & 255);
    if (i < n4x) xd[i] = p;
    else wd[i - n4x] = p;
  }
}

// ---- int8 MFMA GEMM, 256x256 tile, 8 waves, m201-style 4-phase/K-tile ----
// A: [N_TOKENS][IN_F] i8, B: [OUT_F][IN_F] i8; C = A @ B^T, requant epilogue.
__global__ __launch_bounds__(512, 2) void gemm_i8(
    const signed char* __restrict__ A, const signed char* __restrict__ B,
    const int* __restrict__ bias, const float* __restrict__ wscale,
    int* __restrict__ out) {
  // double-buffered K-tiles: compute buf t&1 while staging tile t+1 into buf^1.
  // WAR-safe: buf^1's readers (tile t-1) drained lgkmcnt(0) before the
  // boundary barrier that precedes any tile-t stage issue.
  __shared__ __align__(16) signed char sA[2][BM * BKB];  // 2 x 32 KB
  __shared__ __align__(16) signed char sB[2][BN * BKB];  // 2 x 32 KB

  const int tid = threadIdx.x;
  const int lane = tid & 63;
  const int w = tid >> 6;  // wave 0..7
  const int wr = w >> 2;   // 0..1 : M-panel (128 rows)
  const int wc = w & 3;    // 0..3 : N-panel (64 cols)

  const int brow = blockIdx.y * BM;
  const int bcol = blockIdx.x * BN;

  // Staging: each 8KB group = 64 rows x 128B, 512 threads x 16B.
  // LDS dest linear in tid (gload_lds requirement); bank swizzle via
  // pre-swizzled GLOBAL chunk: physical chunk (tid&7) holds logical chunk
  // (tid&7)^(row&7)  (involution, row&7 == (tid>>3)&7).
  const int grow = tid >> 3;                          // row within group
  const int gchk = ((tid & 7) ^ (grow & 7)) << 4;     // swizzled src byte
  const signed char* gA = A + (size_t)(brow + grow) * IN_F + gchk;
  const signed char* gB = B + (size_t)(bcol + grow) * IN_F + gchk;
  const int lst = tid << 4;                           // dest byte in group
#define GSTR ((size_t)64 * IN_F)                      // group source stride

  // Fragment reads: row = panel + m*16 + (lane&15) -> row&7 == lane&7.
  // logical chunk = ksub*4 + (lane>>4); physical = logical ^ (lane&7).
  const int c0 = (((lane >> 4) ^ (lane & 7)) << 4);   // ksub0 chunk byte
  const int c1 = c0 ^ 64;                             // ksub1 (chunk ^ 4)
  const int rA = (wr * 128 + (lane & 15)) * BKB;
  const int rB = (wc * 64 + (lane & 15)) * BKB;

  int32x4 acc[8][4];
#pragma unroll
  for (int m = 0; m < 8; ++m)
#pragma unroll
    for (int n = 0; n < 4; ++n) acc[m][n] = (int32x4){0, 0, 0, 0};

  // prologue: stage tile 0 fully into buf 0, publish.
#pragma unroll
  for (int i = 0; i < 4; ++i) {
    gload_lds16(gB + i * GSTR, &sB[0][i * 8192 + lst]);
    gload_lds16(gA + i * GSTR, &sA[0][i * 8192 + lst]);
  }
  asm volatile("s_waitcnt vmcnt(0)" ::: "memory");
  __builtin_amdgcn_s_barrier();

  for (int t = 0; t < NKT; ++t) {
    const int buf = t & 1;
    const int nb = buf ^ 1;
    const bool pf = (t < NKT - 1);
    const signed char* srcA = gA + (size_t)(t + 1) * BKB;
    const signed char* srcB = gB + (size_t)(t + 1) * BKB;
    signed char* dA = &sA[nb][lst];
    signed char* dB = &sB[nb][lst];
    int32x4 a[4], b[4];

    // ---- P0: ksub0, m 0-3 (reads 8; stage B0,B2) ----
#pragma unroll
    for (int n = 0; n < 4; ++n) b[n] = *(const int32x4*)&sB[buf][rB + n * 2048 + c0];
#pragma unroll
    for (int m = 0; m < 4; ++m) a[m] = *(const int32x4*)&sA[buf][rA + m * 2048 + c0];
    if (pf) { gload_lds16(srcB, dB); gload_lds16(srcB + 2 * GSTR, dB + 16384); }
    __builtin_amdgcn_s_barrier();
    asm volatile("s_waitcnt lgkmcnt(0)" ::: "memory");
    __builtin_amdgcn_sched_barrier(0);
    __builtin_amdgcn_s_setprio(1);
#pragma unroll
    for (int m = 0; m < 4; ++m)
#pragma unroll
      for (int n = 0; n < 4; ++n)
        acc[m][n] = __builtin_amdgcn_mfma_i32_16x16x64_i8(a[m], b[n], acc[m][n], 0, 0, 0);
    __builtin_amdgcn_s_setprio(0);
    // A1,A3 of THIS tile (issued last tile P3) must land before P1 reads them.
    if (pf) asm volatile("s_waitcnt vmcnt(2)" ::: "memory");
    else    asm volatile("s_waitcnt vmcnt(0)" ::: "memory");
    __builtin_amdgcn_s_barrier();

    // ---- P1: ksub0, m 4-7 (reads 4; stage B1,B3) ----
#pragma unroll
    for (int m = 0; m < 4; ++m) a[m] = *(const int32x4*)&sA[buf][rA + (m + 4) * 2048 + c0];
    if (pf) { gload_lds16(srcB + GSTR, dB + 8192); gload_lds16(srcB + 3 * GSTR, dB + 24576); }
    __builtin_amdgcn_s_barrier();
    asm volatile("s_waitcnt lgkmcnt(0)" ::: "memory");
    __builtin_amdgcn_sched_barrier(0);
    __builtin_amdgcn_s_setprio(1);
#pragma unroll
    for (int m = 0; m < 4; ++m)
#pragma unroll
      for (int n = 0; n < 4; ++n)
        acc[m + 4][n] = __builtin_amdgcn_mfma_i32_16x16x64_i8(a[m], b[n], acc[m + 4][n], 0, 0, 0);
    __builtin_amdgcn_s_setprio(0);
    __builtin_amdgcn_s_barrier();

    // ---- P2: ksub1, m 0-3 (reads 8; stage A0,A2) ----
#pragma unroll
    for (int n = 0; n < 4; ++n) b[n] = *(const int32x4*)&sB[buf][rB + n * 2048 + c1];
#pragma unroll
    for (int m = 0; m < 4; ++m) a[m] = *(const int32x4*)&sA[buf][rA + m * 2048 + c1];
    if (pf) { gload_lds16(srcA, dA); gload_lds16(srcA + 2 * GSTR, dA + 16384); }
    __builtin_amdgcn_s_barrier();
    asm volatile("s_waitcnt lgkmcnt(0)" ::: "memory");
    __builtin_amdgcn_sched_barrier(0);
    __builtin_amdgcn_s_setprio(1);
#pragma unroll
    for (int m = 0; m < 4; ++m)
#pragma unroll
      for (int n = 0; n < 4; ++n)
        acc[m][n] = __builtin_amdgcn_mfma_i32_16x16x64_i8(a[m], b[n], acc[m][n], 0, 0, 0);
    __builtin_amdgcn_s_setprio(0);
    __builtin_amdgcn_s_barrier();

    // ---- P3: ksub1, m 4-7 (reads 4; stage A1,A3) ----
#pragma unroll
    for (int m = 0; m < 4; ++m) a[m] = *(const int32x4*)&sA[buf][rA + (m + 4) * 2048 + c1];
    if (pf) { gload_lds16(srcA + GSTR, dA + 8192); gload_lds16(srcA + 3 * GSTR, dA + 24576); }
    __builtin_amdgcn_s_barrier();
    asm volatile("s_waitcnt lgkmcnt(0)" ::: "memory");
    __builtin_amdgcn_sched_barrier(0);
    __builtin_amdgcn_s_setprio(1);
#pragma unroll
    for (int m = 0; m < 4; ++m)
#pragma unroll
      for (int n = 0; n < 4; ++n)
        acc[m + 4][n] = __builtin_amdgcn_mfma_i32_16x16x64_i8(a[m], b[n], acc[m + 4][n], 0, 0, 0);
    __builtin_amdgcn_s_setprio(0);
    // boundary: everything tile t+1 needs at P0 (B*, A0, A2) landed; A1,A3
    // (just issued) stay in flight -- counted, never 0 mid-loop.
    asm volatile("s_waitcnt vmcnt(2)" ::: "memory");
    __builtin_amdgcn_s_barrier();
  }
#undef GSTR

  // epilogue: C/D layout col=lane&15, row=(lane>>4)*4+reg. OUTPUT IS INT32.
  const int colb = bcol + wc * 64 + (lane & 15);
  const int rowb = brow + wr * 128 + ((lane >> 4) << 2);
#pragma unroll
  for (int n = 0; n < 4; ++n) {
    const int col = colb + n * 16;
    const float s = 0.02f * wscale[col] / 0.05f;
    const int bz = bias[col];
#pragma unroll
    for (int m = 0; m < 8; ++m) {
      const int row0 = rowb + m * 16;
#pragma unroll
      for (int r = 0; r < 4; ++r) {
        float f = (float)(acc[m][n][r] + bz) * s;
        f = rintf(f);                        // round-half-even == jnp.round
        f = fminf(127.f, fmaxf(-128.f, f));  // clip
        out[(size_t)(row0 + r) * OUT_F + col] = (int)f;
      }
    }
  }
}

extern "C" void kernel_launch(void* const* d_in, const int* in_sizes, int n_in,
                              void* d_out, int out_size, void* d_ws, size_t ws_size,
                              hipStream_t stream) {
  const int* x = (const int*)d_in[0];        // [8192,4096] values in [-128,127]
  const int* w = (const int*)d_in[1];        // [4096,4096]
  const int* bias = (const int*)d_in[2];     // [4096]
  const float* wsc = (const float*)d_in[3];  // [4096]
  int* out = (int*)d_out;

  signed char* xp = (signed char*)d_ws;            // 32 MB
  signed char* wp = xp + (size_t)N_TOKENS * IN_F;  // 16 MB

  const int n4x = N_TOKENS * IN_F / 4;
  const int n4w = OUT_F * IN_F / 4;
  const int n4tot = n4x + n4w;

  pack_kernel<<<2048, 256, 0, stream>>>((const int4*)x, (const int4*)w,
                                        (uchar4*)xp, (uchar4*)wp, n4x, n4tot);

  dim3 grid(OUT_F / BN, N_TOKENS / BM);  // (16, 32) = 512 blocks
  gemm_i8<<<grid, dim3(512), 0, stream>>>(xp, wp, bias, wsc, out);
}